// Round 1
// baseline (909.136 us; speedup 1.0000x reference)
//
#include <hip/hip_runtime.h>
#include <hip/hip_bf16.h>
#include <math.h>

// ---------------- problem constants ----------------
#define D_MODEL 1024
#define N_EXP   8
#define D_FF    4096
#define T_TOK   8192
#define NPAIR   (T_TOK * 2)              // 16384 token-expert pairs (top-2)
#define CAP_ROWS (NPAIR + N_EXP * 128)   // 17408: worst-case padded rows
#define MAX_TILES (CAP_ROWS / 128)       // 136 M-tiles worst case

typedef __attribute__((ext_vector_type(4))) float  f32x4;
typedef __attribute__((ext_vector_type(8))) __bf16 bf16x8;
typedef __attribute__((ext_vector_type(4))) __bf16 bf16x4;

// ---------------- workspace layout (bytes) ----------------
// W1T  bf16 [E][F][D]  : 67108864   (aliased by Ypair after GEMM1 is done)
// W2T  bf16 [E][D][F]  : 67108864
// H    bf16 [CAP][F]   : 142606336
// XR   bf16 [CAP][D]   : 35651584
// meta                 : ~203KB
#define OFF_W1T   0
#define OFF_W2T   67108864
#define OFF_H     134217728
#define OFF_XR    276824064
#define OFF_META  312475648
#define M_PAIREXP 0         // int[16384]
#define M_PAIRW   65536     // float[16384]
#define M_ROW2P   131072    // int[17408]
#define M_COUNTS  200704    // int[8]
#define M_PADST   200736    // int[8]
#define M_CURSOR  200768    // int[8*32] (padded lines)
#define M_T2E     201792    // int[136]
#define M_TROW    202336    // int[136]

__device__ __forceinline__ void async_copy16(const void* g, void* s) {
  __builtin_amdgcn_global_load_lds(
      (const __attribute__((address_space(1))) void*)g,
      (__attribute__((address_space(3))) void*)s, 16, 0, 0);
}

__device__ __forceinline__ float gelu_exact(float v) {
  return 0.5f * v * (1.0f + erff(v * 0.70710678118654752440f));
}

// ---------------- gating: logits, softmax, top-2 ----------------
__global__ void k_gate(const float* __restrict__ x, const float* __restrict__ Wg,
                       const float* __restrict__ bg, float* __restrict__ logits_out,
                       int* __restrict__ pairExpert, float* __restrict__ pairW) {
  const int t    = blockIdx.x * 4 + (threadIdx.x >> 6);
  const int lane = threadIdx.x & 63;
  const float* xp = x + (size_t)t * D_MODEL;
  float acc[8];
#pragma unroll
  for (int e = 0; e < 8; e++) acc[e] = 0.f;
#pragma unroll
  for (int i = 0; i < 16; i++) {
    int d = i * 64 + lane;
    float xv = xp[d];
    const float4* wr = (const float4*)(Wg + d * 8);
    float4 w0 = wr[0], w1 = wr[1];
    acc[0] += xv * w0.x; acc[1] += xv * w0.y; acc[2] += xv * w0.z; acc[3] += xv * w0.w;
    acc[4] += xv * w1.x; acc[5] += xv * w1.y; acc[6] += xv * w1.z; acc[7] += xv * w1.w;
  }
#pragma unroll
  for (int e = 0; e < 8; e++)
#pragma unroll
    for (int off = 32; off > 0; off >>= 1) acc[e] += __shfl_down(acc[e], off);
  if (lane == 0) {
    float l[8];
#pragma unroll
    for (int e = 0; e < 8; e++) { l[e] = acc[e] + bg[e]; logits_out[t * 8 + e] = l[e]; }
    float m = l[0];
#pragma unroll
    for (int e = 1; e < 8; e++) m = fmaxf(m, l[e]);
    float p[8], s = 0.f;
#pragma unroll
    for (int e = 0; e < 8; e++) { p[e] = expf(l[e] - m); s += p[e]; }
    float inv = 1.0f / s;
    int i1 = 0;
#pragma unroll
    for (int e = 1; e < 8; e++) if (l[e] > l[i1]) i1 = e;
    int i2 = (i1 == 0) ? 1 : 0;
#pragma unroll
    for (int e = 0; e < 8; e++) if (e != i1 && l[e] > l[i2]) i2 = e;
    pairExpert[t * 2 + 0] = i1; pairW[t * 2 + 0] = p[i1] * inv;
    pairExpert[t * 2 + 1] = i2; pairW[t * 2 + 1] = p[i2] * inv;
  }
}

// ---------------- routing metadata ----------------
__global__ void k_init(int* __restrict__ row2pair) {
  int i = blockIdx.x * 256 + threadIdx.x;
  if (i < CAP_ROWS) row2pair[i] = -1;
}

__global__ void k_offsets(const int* __restrict__ pairExpert, int* __restrict__ counts,
                          int* __restrict__ padStart, int* __restrict__ cursor,
                          int* __restrict__ t2e, int* __restrict__ trow) {
  __shared__ int hist[8];
  int tid = threadIdx.x;
  if (tid < 8) hist[tid] = 0;
  __syncthreads();
  for (int i = tid; i < NPAIR; i += 256) atomicAdd(&hist[pairExpert[i]], 1);
  __syncthreads();
  if (tid == 0) {
    int run = 0, nt = 0;
    for (int e = 0; e < 8; e++) {
      counts[e] = hist[e]; padStart[e] = run; cursor[e * 32] = 0;
      int tiles = (hist[e] + 127) >> 7;
      for (int i = 0; i < tiles; i++) { t2e[nt] = e; trow[nt] = run + i * 128; nt++; }
      run += tiles * 128;
    }
    for (; nt < MAX_TILES; nt++) t2e[nt] = -1;
  }
}

__global__ void k_place(const int* __restrict__ pairExpert, const int* __restrict__ padStart,
                        int* __restrict__ cursor, int* __restrict__ row2pair) {
  int p = blockIdx.x * 256 + threadIdx.x;
  if (p >= NPAIR) return;
  int e = pairExpert[p];
  int r = atomicAdd(&cursor[e * 32], 1);
  row2pair[padStart[e] + r] = p;
}

// ---------------- gather x rows -> routed bf16 ----------------
__global__ void k_gather(const float* __restrict__ x, const int* __restrict__ row2pair,
                         __bf16* __restrict__ XR) {
  int row = blockIdx.x;
  int pair = row2pair[row];
  int c = threadIdx.x * 4;
  __bf16* dst = XR + (size_t)row * D_MODEL + c;
  if (pair < 0) {
    bf16x4 z = {(__bf16)0.f, (__bf16)0.f, (__bf16)0.f, (__bf16)0.f};
    *(bf16x4*)dst = z;
  } else {
    int t = pair >> 1;
    float4 v = *(const float4*)(x + (size_t)t * D_MODEL + c);
    bf16x4 o = {(__bf16)v.x, (__bf16)v.y, (__bf16)v.z, (__bf16)v.w};
    *(bf16x4*)dst = o;
  }
}

// ---------------- transpose-convert weights: in fp32 [E][R][C] -> out bf16 [E][C][R] ----
__global__ void k_convT(const float* __restrict__ in, __bf16* __restrict__ out,
                        int R, int C) {
  __shared__ __bf16 tile[64][65];
  int e = blockIdx.z;
  const float* ip = in + (size_t)e * R * C;
  __bf16* op = out + (size_t)e * R * C;
  int r0 = blockIdx.y * 64, c0 = blockIdx.x * 64;
#pragma unroll
  for (int i = 0; i < 16; i++) {
    int lin = threadIdx.x + i * 256;
    int lr = lin >> 6, lc = lin & 63;
    tile[lr][lc] = (__bf16)ip[(size_t)(r0 + lr) * C + c0 + lc];
  }
  __syncthreads();
#pragma unroll
  for (int i = 0; i < 16; i++) {
    int lin = threadIdx.x + i * 256;
    int lc = lin >> 6, lr = lin & 63;
    op[(size_t)(c0 + lc) * R + r0 + lr] = tile[lr][lc];
  }
}

// ---------------- GEMM1: h = gelu(XR @ W1[e] + b1[e]) -> bf16 ----------------
// A: XR [CAP][1024] bf16, B: W1T [E][4096][1024] bf16 (n-major), C: H [CAP][4096] bf16
__global__ __launch_bounds__(256) void k_gemm1(
    const __bf16* __restrict__ XR, const __bf16* __restrict__ W1T,
    const float* __restrict__ b1, __bf16* __restrict__ H,
    const int* __restrict__ t2e, const int* __restrict__ trow) {
  __shared__ __align__(16) __bf16 sA[128 * 32];
  __shared__ __align__(16) __bf16 sB[128 * 32];
  const int mt = blockIdx.y;
  const int e = t2e[mt];
  if (e < 0) return;
  const int rowBase = trow[mt];
  const int n0 = blockIdx.x * 128;
  const __bf16* Ab = XR + (size_t)rowBase * D_MODEL;
  const __bf16* Bb = W1T + (size_t)e * D_FF * D_MODEL + (size_t)n0 * D_MODEL;

  const int tid = threadIdx.x;
  const int rA = tid >> 2;
  const int kA = (tid & 3) * 8;
  const int lane = tid & 63;
  const int wave = tid >> 6;
  const int wm = (wave >> 1) * 64, wn = (wave & 1) * 64;
  const int lrow = lane & 15, quad = lane >> 4;

  f32x4 acc[4][4];
#pragma unroll
  for (int i = 0; i < 4; i++)
#pragma unroll
    for (int j = 0; j < 4; j++) acc[i][j] = (f32x4){0.f, 0.f, 0.f, 0.f};

  for (int k0 = 0; k0 < D_MODEL; k0 += 32) {
    async_copy16(Ab + (size_t)rA * D_MODEL + k0 + kA,        (char*)sA + tid * 16);
    async_copy16(Ab + (size_t)(rA + 64) * D_MODEL + k0 + kA, (char*)sA + tid * 16 + 4096);
    async_copy16(Bb + (size_t)rA * D_MODEL + k0 + kA,        (char*)sB + tid * 16);
    async_copy16(Bb + (size_t)(rA + 64) * D_MODEL + k0 + kA, (char*)sB + tid * 16 + 4096);
    __syncthreads();
    bf16x8 af[4], bfr[4];
#pragma unroll
    for (int i = 0; i < 4; i++) af[i]  = *(const bf16x8*)(sA + (wm + i * 16 + lrow) * 32 + quad * 8);
#pragma unroll
    for (int j = 0; j < 4; j++) bfr[j] = *(const bf16x8*)(sB + (wn + j * 16 + lrow) * 32 + quad * 8);
#pragma unroll
    for (int i = 0; i < 4; i++)
#pragma unroll
      for (int j = 0; j < 4; j++)
        acc[i][j] = __builtin_amdgcn_mfma_f32_16x16x32_bf16(af[i], bfr[j], acc[i][j], 0, 0, 0);
    __syncthreads();
  }
#pragma unroll
  for (int j = 0; j < 4; j++) {
    int col = n0 + wn + j * 16 + lrow;
    float bias = b1[e * D_FF + col];
#pragma unroll
    for (int i = 0; i < 4; i++) {
      size_t rowg = (size_t)rowBase + wm + i * 16 + quad * 4;
#pragma unroll
      for (int r = 0; r < 4; r++) {
        float v = acc[i][j][r] + bias;
        H[(rowg + r) * D_FF + col] = (__bf16)gelu_exact(v);
      }
    }
  }
}

// ---------------- GEMM2: y = (H @ W2[e] + b2[e]) * w  -> Ypair slot ----------------
__global__ __launch_bounds__(256) void k_gemm2(
    const __bf16* __restrict__ H, const __bf16* __restrict__ W2T,
    const float* __restrict__ b2, float* __restrict__ Ypair,
    const int* __restrict__ row2pair, const float* __restrict__ pairW,
    const int* __restrict__ t2e, const int* __restrict__ trow) {
  __shared__ __align__(16) __bf16 sA[128 * 32];
  __shared__ __align__(16) __bf16 sB[128 * 32];
  const int mt = blockIdx.y;
  const int e = t2e[mt];
  if (e < 0) return;
  const int rowBase = trow[mt];
  const int n0 = blockIdx.x * 128;
  const __bf16* Ab = H + (size_t)rowBase * D_FF;
  const __bf16* Bb = W2T + (size_t)e * D_MODEL * D_FF + (size_t)n0 * D_FF;

  const int tid = threadIdx.x;
  const int rA = tid >> 2;
  const int kA = (tid & 3) * 8;
  const int lane = tid & 63;
  const int wave = tid >> 6;
  const int wm = (wave >> 1) * 64, wn = (wave & 1) * 64;
  const int lrow = lane & 15, quad = lane >> 4;

  f32x4 acc[4][4];
#pragma unroll
  for (int i = 0; i < 4; i++)
#pragma unroll
    for (int j = 0; j < 4; j++) acc[i][j] = (f32x4){0.f, 0.f, 0.f, 0.f};

  for (int k0 = 0; k0 < D_FF; k0 += 32) {
    async_copy16(Ab + (size_t)rA * D_FF + k0 + kA,        (char*)sA + tid * 16);
    async_copy16(Ab + (size_t)(rA + 64) * D_FF + k0 + kA, (char*)sA + tid * 16 + 4096);
    async_copy16(Bb + (size_t)rA * D_FF + k0 + kA,        (char*)sB + tid * 16);
    async_copy16(Bb + (size_t)(rA + 64) * D_FF + k0 + kA, (char*)sB + tid * 16 + 4096);
    __syncthreads();
    bf16x8 af[4], bfr[4];
#pragma unroll
    for (int i = 0; i < 4; i++) af[i]  = *(const bf16x8*)(sA + (wm + i * 16 + lrow) * 32 + quad * 8);
#pragma unroll
    for (int j = 0; j < 4; j++) bfr[j] = *(const bf16x8*)(sB + (wn + j * 16 + lrow) * 32 + quad * 8);
#pragma unroll
    for (int i = 0; i < 4; i++)
#pragma unroll
      for (int j = 0; j < 4; j++)
        acc[i][j] = __builtin_amdgcn_mfma_f32_16x16x32_bf16(af[i], bfr[j], acc[i][j], 0, 0, 0);
    __syncthreads();
  }
  float bias[4];
#pragma unroll
  for (int j = 0; j < 4; j++) bias[j] = b2[e * D_MODEL + n0 + wn + j * 16 + lrow];
#pragma unroll
  for (int i = 0; i < 4; i++) {
#pragma unroll
    for (int r = 0; r < 4; r++) {
      int rglob = rowBase + wm + i * 16 + quad * 4 + r;
      int pair = row2pair[rglob];
      if (pair < 0) continue;
      float w = pairW[pair];
#pragma unroll
      for (int j = 0; j < 4; j++) {
        int col = n0 + wn + j * 16 + lrow;
        Ypair[(size_t)pair * D_MODEL + col] = w * (acc[i][j][r] + bias[j]);
      }
    }
  }
}

// ---------------- combine: out[t] = y[t,slot0] + y[t,slot1] ----------------
__global__ void k_combine(const float* __restrict__ Ypair, float* __restrict__ out) {
  size_t idx = (size_t)blockIdx.x * 256 + threadIdx.x;  // t*256 + c4
  size_t t = idx >> 8, c4 = idx & 255;
  const float4* y4 = (const float4*)Ypair;
  float4 a = y4[(2 * t) * 256 + c4];
  float4 b = y4[(2 * t + 1) * 256 + c4];
  float4 o = {a.x + b.x, a.y + b.y, a.z + b.z, a.w + b.w};
  ((float4*)out)[idx] = o;
}

extern "C" void kernel_launch(void* const* d_in, const int* in_sizes, int n_in,
                              void* d_out, int out_size, void* d_ws, size_t ws_size,
                              hipStream_t stream) {
  const float* x  = (const float*)d_in[0];
  const float* Wg = (const float*)d_in[1];
  const float* bg = (const float*)d_in[2];
  const float* W1 = (const float*)d_in[3];
  const float* b1 = (const float*)d_in[4];
  const float* W2 = (const float*)d_in[5];
  const float* b2 = (const float*)d_in[6];
  float* out        = (float*)d_out;
  float* logits_out = out + (size_t)T_TOK * D_MODEL;

  char* ws = (char*)d_ws;
  __bf16* W1T = (__bf16*)(ws + OFF_W1T);
  __bf16* W2T = (__bf16*)(ws + OFF_W2T);
  __bf16* H   = (__bf16*)(ws + OFF_H);
  __bf16* XR  = (__bf16*)(ws + OFF_XR);
  float* Ypair = (float*)(ws + OFF_W1T);  // alias: W1T dead after GEMM1
  char* meta = ws + OFF_META;
  int*   pairExpert = (int*)(meta + M_PAIREXP);
  float* pairW      = (float*)(meta + M_PAIRW);
  int*   row2pair   = (int*)(meta + M_ROW2P);
  int*   counts     = (int*)(meta + M_COUNTS);
  int*   padStart   = (int*)(meta + M_PADST);
  int*   cursor     = (int*)(meta + M_CURSOR);
  int*   t2e        = (int*)(meta + M_T2E);
  int*   trow       = (int*)(meta + M_TROW);

  // weight convert+transpose: W1 [E][1024][4096] -> W1T [E][4096][1024]
  k_convT<<<dim3(D_FF / 64, D_MODEL / 64, N_EXP), 256, 0, stream>>>(W1, W1T, D_MODEL, D_FF);
  // W2 [E][4096][1024] -> W2T [E][1024][4096]
  k_convT<<<dim3(D_MODEL / 64, D_FF / 64, N_EXP), 256, 0, stream>>>(W2, W2T, D_FF, D_MODEL);

  k_init<<<(CAP_ROWS + 255) / 256, 256, 0, stream>>>(row2pair);
  k_gate<<<T_TOK / 4, 256, 0, stream>>>(x, Wg, bg, logits_out, pairExpert, pairW);
  k_offsets<<<1, 256, 0, stream>>>(pairExpert, counts, padStart, cursor, t2e, trow);
  k_place<<<NPAIR / 256, 256, 0, stream>>>(pairExpert, padStart, cursor, row2pair);
  k_gather<<<CAP_ROWS, 256, 0, stream>>>(x, row2pair, XR);

  k_gemm1<<<dim3(D_FF / 128, MAX_TILES), 256, 0, stream>>>(XR, W1T, b1, H, t2e, trow);
  k_gemm2<<<dim3(D_MODEL / 128, MAX_TILES), 256, 0, stream>>>(H, W2T, b2, Ypair, row2pair, pairW, t2e, trow);
  k_combine<<<(size_t)T_TOK * D_MODEL / 4 / 256, 256, 0, stream>>>(Ypair, out);
}

// Round 2
// 890.642 us; speedup vs baseline: 1.0208x; 1.0208x over previous
//
#include <hip/hip_runtime.h>
#include <hip/hip_bf16.h>
#include <math.h>

// ---------------- problem constants ----------------
#define D_MODEL 1024
#define N_EXP   8
#define D_FF    4096
#define T_TOK   8192
#define NPAIR   (T_TOK * 2)              // 16384 token-expert pairs (top-2)
#define CAP_ROWS (NPAIR + N_EXP * 128)   // 17408: worst-case padded rows
#define MAX_TILES (CAP_ROWS / 128)       // 136 M-tiles worst case (divisible by 8)

typedef __attribute__((ext_vector_type(4))) float  f32x4;
typedef __attribute__((ext_vector_type(8))) __bf16 bf16x8;
typedef __attribute__((ext_vector_type(4))) __bf16 bf16x4;

// ---------------- workspace layout (bytes) ----------------
#define OFF_W1T   0
#define OFF_W2T   67108864
#define OFF_H     134217728
#define OFF_XR    276824064
#define OFF_META  312475648
#define M_PAIREXP 0         // int[16384]
#define M_PAIRW   65536     // float[16384]
#define M_ROW2P   131072    // int[17408]
#define M_COUNTS  200704    // int[8]
#define M_PADST   200736    // int[8]
#define M_CURSOR  200768    // int[8*32] (padded lines)
#define M_T2E     201792    // int[136]
#define M_TROW    202336    // int[136]

__device__ __forceinline__ void async_copy16(const void* g, void* s) {
  __builtin_amdgcn_global_load_lds(
      (const __attribute__((address_space(1))) void*)g,
      (__attribute__((address_space(3))) void*)s, 16, 0, 0);
}

__device__ __forceinline__ float gelu_exact(float v) {
  return 0.5f * v * (1.0f + erff(v * 0.70710678118654752440f));
}

// ---------------- gating: logits, softmax, top-2 ----------------
__global__ void k_gate(const float* __restrict__ x, const float* __restrict__ Wg,
                       const float* __restrict__ bg, float* __restrict__ logits_out,
                       int* __restrict__ pairExpert, float* __restrict__ pairW) {
  const int t    = blockIdx.x * 4 + (threadIdx.x >> 6);
  const int lane = threadIdx.x & 63;
  const float* xp = x + (size_t)t * D_MODEL;
  float acc[8];
#pragma unroll
  for (int e = 0; e < 8; e++) acc[e] = 0.f;
#pragma unroll
  for (int i = 0; i < 16; i++) {
    int d = i * 64 + lane;
    float xv = xp[d];
    const float4* wr = (const float4*)(Wg + d * 8);
    float4 w0 = wr[0], w1 = wr[1];
    acc[0] += xv * w0.x; acc[1] += xv * w0.y; acc[2] += xv * w0.z; acc[3] += xv * w0.w;
    acc[4] += xv * w1.x; acc[5] += xv * w1.y; acc[6] += xv * w1.z; acc[7] += xv * w1.w;
  }
#pragma unroll
  for (int e = 0; e < 8; e++)
#pragma unroll
    for (int off = 32; off > 0; off >>= 1) acc[e] += __shfl_down(acc[e], off);
  if (lane == 0) {
    float l[8];
#pragma unroll
    for (int e = 0; e < 8; e++) { l[e] = acc[e] + bg[e]; logits_out[t * 8 + e] = l[e]; }
    float m = l[0];
#pragma unroll
    for (int e = 1; e < 8; e++) m = fmaxf(m, l[e]);
    float p[8], s = 0.f;
#pragma unroll
    for (int e = 0; e < 8; e++) { p[e] = expf(l[e] - m); s += p[e]; }
    float inv = 1.0f / s;
    int i1 = 0;
#pragma unroll
    for (int e = 1; e < 8; e++) if (l[e] > l[i1]) i1 = e;
    int i2 = (i1 == 0) ? 1 : 0;
#pragma unroll
    for (int e = 0; e < 8; e++) if (e != i1 && l[e] > l[i2]) i2 = e;
    pairExpert[t * 2 + 0] = i1; pairW[t * 2 + 0] = p[i1] * inv;
    pairExpert[t * 2 + 1] = i2; pairW[t * 2 + 1] = p[i2] * inv;
  }
}

// ---------------- routing metadata ----------------
__global__ void k_init(int* __restrict__ row2pair) {
  int i = blockIdx.x * 256 + threadIdx.x;
  if (i < CAP_ROWS) row2pair[i] = -1;
}

__global__ void k_offsets(const int* __restrict__ pairExpert, int* __restrict__ counts,
                          int* __restrict__ padStart, int* __restrict__ cursor,
                          int* __restrict__ t2e, int* __restrict__ trow) {
  __shared__ int hist[8];
  int tid = threadIdx.x;
  if (tid < 8) hist[tid] = 0;
  __syncthreads();
  for (int i = tid; i < NPAIR; i += 256) atomicAdd(&hist[pairExpert[i]], 1);
  __syncthreads();
  if (tid == 0) {
    int run = 0, nt = 0;
    for (int e = 0; e < 8; e++) {
      counts[e] = hist[e]; padStart[e] = run; cursor[e * 32] = 0;
      int tiles = (hist[e] + 127) >> 7;
      for (int i = 0; i < tiles; i++) { t2e[nt] = e; trow[nt] = run + i * 128; nt++; }
      run += tiles * 128;
    }
    for (; nt < MAX_TILES; nt++) t2e[nt] = -1;
  }
}

__global__ void k_place(const int* __restrict__ pairExpert, const int* __restrict__ padStart,
                        int* __restrict__ cursor, int* __restrict__ row2pair) {
  int p = blockIdx.x * 256 + threadIdx.x;
  if (p >= NPAIR) return;
  int e = pairExpert[p];
  int r = atomicAdd(&cursor[e * 32], 1);
  row2pair[padStart[e] + r] = p;
}

// ---------------- gather x rows -> routed bf16 ----------------
__global__ void k_gather(const float* __restrict__ x, const int* __restrict__ row2pair,
                         __bf16* __restrict__ XR) {
  int row = blockIdx.x;
  int pair = row2pair[row];
  int c = threadIdx.x * 4;
  __bf16* dst = XR + (size_t)row * D_MODEL + c;
  if (pair < 0) {
    bf16x4 z = {(__bf16)0.f, (__bf16)0.f, (__bf16)0.f, (__bf16)0.f};
    *(bf16x4*)dst = z;
  } else {
    int t = pair >> 1;
    float4 v = *(const float4*)(x + (size_t)t * D_MODEL + c);
    bf16x4 o = {(__bf16)v.x, (__bf16)v.y, (__bf16)v.z, (__bf16)v.w};
    *(bf16x4*)dst = o;
  }
}

// ---------------- transpose-convert weights: in fp32 [E][R][C] -> out bf16 [E][C][R] ----
__global__ void k_convT(const float* __restrict__ in, __bf16* __restrict__ out,
                        int R, int C) {
  __shared__ __bf16 tile[64][65];
  int e = blockIdx.z;
  const float* ip = in + (size_t)e * R * C;
  __bf16* op = out + (size_t)e * R * C;
  int r0 = blockIdx.y * 64, c0 = blockIdx.x * 64;
#pragma unroll
  for (int i = 0; i < 16; i++) {
    int lin = threadIdx.x + i * 256;
    int lr = lin >> 6, lc = lin & 63;
    tile[lr][lc] = (__bf16)ip[(size_t)(r0 + lr) * C + c0 + lc];
  }
  __syncthreads();
#pragma unroll
  for (int i = 0; i < 16; i++) {
    int lin = threadIdx.x + i * 256;
    int lc = lin >> 6, lr = lin & 63;
    op[(size_t)(c0 + lc) * R + r0 + lr] = tile[lr][lc];
  }
}

// ---------------- GEMM1: h = gelu(XR @ W1[e] + b1[e]) -> bf16 ----------------
// A: XR [CAP][1024] bf16, B: W1T [E][4096][1024] bf16 (n-major), C: H [CAP][4096] bf16
__global__ __launch_bounds__(256) void k_gemm1(
    const __bf16* __restrict__ XR, const __bf16* __restrict__ W1T,
    const float* __restrict__ b1, __bf16* __restrict__ H,
    const int* __restrict__ t2e, const int* __restrict__ trow) {
  __shared__ __align__(16) __bf16 sA[128 * 32];
  __shared__ __align__(16) __bf16 sB[128 * 32];
  const int mt = blockIdx.y;
  const int e = t2e[mt];
  if (e < 0) return;
  const int rowBase = trow[mt];
  const int n0 = blockIdx.x * 128;
  const __bf16* Ab = XR + (size_t)rowBase * D_MODEL;
  const __bf16* Bb = W1T + (size_t)e * D_FF * D_MODEL + (size_t)n0 * D_MODEL;

  const int tid = threadIdx.x;
  const int rA = tid >> 2;
  const int kA = (tid & 3) * 8;
  const int lane = tid & 63;
  const int wave = tid >> 6;
  const int wm = (wave >> 1) * 64, wn = (wave & 1) * 64;
  const int lrow = lane & 15, quad = lane >> 4;

  f32x4 acc[4][4];
#pragma unroll
  for (int i = 0; i < 4; i++)
#pragma unroll
    for (int j = 0; j < 4; j++) acc[i][j] = (f32x4){0.f, 0.f, 0.f, 0.f};

  for (int k0 = 0; k0 < D_MODEL; k0 += 32) {
    async_copy16(Ab + (size_t)rA * D_MODEL + k0 + kA,        (char*)sA + tid * 16);
    async_copy16(Ab + (size_t)(rA + 64) * D_MODEL + k0 + kA, (char*)sA + tid * 16 + 4096);
    async_copy16(Bb + (size_t)rA * D_MODEL + k0 + kA,        (char*)sB + tid * 16);
    async_copy16(Bb + (size_t)(rA + 64) * D_MODEL + k0 + kA, (char*)sB + tid * 16 + 4096);
    __syncthreads();
    bf16x8 af[4], bfr[4];
#pragma unroll
    for (int i = 0; i < 4; i++) af[i]  = *(const bf16x8*)(sA + (wm + i * 16 + lrow) * 32 + quad * 8);
#pragma unroll
    for (int j = 0; j < 4; j++) bfr[j] = *(const bf16x8*)(sB + (wn + j * 16 + lrow) * 32 + quad * 8);
#pragma unroll
    for (int i = 0; i < 4; i++)
#pragma unroll
      for (int j = 0; j < 4; j++)
        acc[i][j] = __builtin_amdgcn_mfma_f32_16x16x32_bf16(af[i], bfr[j], acc[i][j], 0, 0, 0);
    __syncthreads();
  }
#pragma unroll
  for (int j = 0; j < 4; j++) {
    int col = n0 + wn + j * 16 + lrow;
    float bias = b1[e * D_FF + col];
#pragma unroll
    for (int i = 0; i < 4; i++) {
      size_t rowg = (size_t)rowBase + wm + i * 16 + quad * 4;
#pragma unroll
      for (int r = 0; r < 4; r++) {
        float v = acc[i][j][r] + bias;
        H[(rowg + r) * D_FF + col] = (__bf16)gelu_exact(v);
      }
    }
  }
}

// ---------------- GEMM2: y = (H @ W2[e] + b2[e]) * w  -> Ypair slot ----------------
// 1D grid, XCD-aware swizzle: XCD = mt % 8, n-tiles iterate fastest within an XCD
// so each XCD's resident set = 8 m-tiles x all 8 n-tiles -> H k-slices fetched once
// per XCD-group and shared by the 8 co-resident n-blocks.
__global__ __launch_bounds__(256) void k_gemm2(
    const __bf16* __restrict__ H, const __bf16* __restrict__ W2T,
    const float* __restrict__ b2, float* __restrict__ Ypair,
    const int* __restrict__ row2pair, const float* __restrict__ pairW,
    const int* __restrict__ t2e, const int* __restrict__ trow) {
  __shared__ __align__(16) __bf16 sA[128 * 32];
  __shared__ __align__(16) __bf16 sB[128 * 32];
  const int b = blockIdx.x;
  const int mt = (b >> 6) * 8 + (b & 7);   // XCD = b%8 = mt%8
  const int nb = (b >> 3) & 7;             // n-tile, fastest within XCD
  const int e = t2e[mt];
  if (e < 0) return;
  const int rowBase = trow[mt];
  const int n0 = nb * 128;
  const __bf16* Ab = H + (size_t)rowBase * D_FF;
  const __bf16* Bb = W2T + (size_t)e * D_MODEL * D_FF + (size_t)n0 * D_FF;

  const int tid = threadIdx.x;
  const int rA = tid >> 2;
  const int kA = (tid & 3) * 8;
  const int lane = tid & 63;
  const int wave = tid >> 6;
  const int wm = (wave >> 1) * 64, wn = (wave & 1) * 64;
  const int lrow = lane & 15, quad = lane >> 4;

  f32x4 acc[4][4];
#pragma unroll
  for (int i = 0; i < 4; i++)
#pragma unroll
    for (int j = 0; j < 4; j++) acc[i][j] = (f32x4){0.f, 0.f, 0.f, 0.f};

  for (int k0 = 0; k0 < D_FF; k0 += 32) {
    async_copy16(Ab + (size_t)rA * D_FF + k0 + kA,        (char*)sA + tid * 16);
    async_copy16(Ab + (size_t)(rA + 64) * D_FF + k0 + kA, (char*)sA + tid * 16 + 4096);
    async_copy16(Bb + (size_t)rA * D_FF + k0 + kA,        (char*)sB + tid * 16);
    async_copy16(Bb + (size_t)(rA + 64) * D_FF + k0 + kA, (char*)sB + tid * 16 + 4096);
    __syncthreads();
    bf16x8 af[4], bfr[4];
#pragma unroll
    for (int i = 0; i < 4; i++) af[i]  = *(const bf16x8*)(sA + (wm + i * 16 + lrow) * 32 + quad * 8);
#pragma unroll
    for (int j = 0; j < 4; j++) bfr[j] = *(const bf16x8*)(sB + (wn + j * 16 + lrow) * 32 + quad * 8);
#pragma unroll
    for (int i = 0; i < 4; i++)
#pragma unroll
      for (int j = 0; j < 4; j++)
        acc[i][j] = __builtin_amdgcn_mfma_f32_16x16x32_bf16(af[i], bfr[j], acc[i][j], 0, 0, 0);
    __syncthreads();
  }
  float bias[4];
#pragma unroll
  for (int j = 0; j < 4; j++) bias[j] = b2[e * D_MODEL + n0 + wn + j * 16 + lrow];
#pragma unroll
  for (int i = 0; i < 4; i++) {
#pragma unroll
    for (int r = 0; r < 4; r++) {
      int rglob = rowBase + wm + i * 16 + quad * 4 + r;
      int pair = row2pair[rglob];
      if (pair < 0) continue;
      float w = pairW[pair];
#pragma unroll
      for (int j = 0; j < 4; j++) {
        int col = n0 + wn + j * 16 + lrow;
        Ypair[(size_t)pair * D_MODEL + col] = w * (acc[i][j][r] + bias[j]);
      }
    }
  }
}

// ---------------- combine: out[t] = y[t,slot0] + y[t,slot1] ----------------
__global__ void k_combine(const float* __restrict__ Ypair, float* __restrict__ out) {
  size_t idx = (size_t)blockIdx.x * 256 + threadIdx.x;  // t*256 + c4
  size_t t = idx >> 8, c4 = idx & 255;
  const float4* y4 = (const float4*)Ypair;
  float4 a = y4[(2 * t) * 256 + c4];
  float4 b = y4[(2 * t + 1) * 256 + c4];
  float4 o = {a.x + b.x, a.y + b.y, a.z + b.z, a.w + b.w};
  ((float4*)out)[idx] = o;
}

extern "C" void kernel_launch(void* const* d_in, const int* in_sizes, int n_in,
                              void* d_out, int out_size, void* d_ws, size_t ws_size,
                              hipStream_t stream) {
  const float* x  = (const float*)d_in[0];
  const float* Wg = (const float*)d_in[1];
  const float* bg = (const float*)d_in[2];
  const float* W1 = (const float*)d_in[3];
  const float* b1 = (const float*)d_in[4];
  const float* W2 = (const float*)d_in[5];
  const float* b2 = (const float*)d_in[6];
  float* out        = (float*)d_out;
  float* logits_out = out + (size_t)T_TOK * D_MODEL;

  char* ws = (char*)d_ws;
  __bf16* W1T = (__bf16*)(ws + OFF_W1T);
  __bf16* W2T = (__bf16*)(ws + OFF_W2T);
  __bf16* H   = (__bf16*)(ws + OFF_H);
  __bf16* XR  = (__bf16*)(ws + OFF_XR);
  float* Ypair = (float*)(ws + OFF_W1T);  // alias: W1T dead after GEMM1
  char* meta = ws + OFF_META;
  int*   pairExpert = (int*)(meta + M_PAIREXP);
  float* pairW      = (float*)(meta + M_PAIRW);
  int*   row2pair   = (int*)(meta + M_ROW2P);
  int*   counts     = (int*)(meta + M_COUNTS);
  int*   padStart   = (int*)(meta + M_PADST);
  int*   cursor     = (int*)(meta + M_CURSOR);
  int*   t2e        = (int*)(meta + M_T2E);
  int*   trow       = (int*)(meta + M_TROW);

  // weight convert+transpose: W1 [E][1024][4096] -> W1T [E][4096][1024]
  k_convT<<<dim3(D_FF / 64, D_MODEL / 64, N_EXP), 256, 0, stream>>>(W1, W1T, D_MODEL, D_FF);
  // W2 [E][4096][1024] -> W2T [E][1024][4096]
  k_convT<<<dim3(D_MODEL / 64, D_FF / 64, N_EXP), 256, 0, stream>>>(W2, W2T, D_FF, D_MODEL);

  k_init<<<(CAP_ROWS + 255) / 256, 256, 0, stream>>>(row2pair);
  k_gate<<<T_TOK / 4, 256, 0, stream>>>(x, Wg, bg, logits_out, pairExpert, pairW);
  k_offsets<<<1, 256, 0, stream>>>(pairExpert, counts, padStart, cursor, t2e, trow);
  k_place<<<NPAIR / 256, 256, 0, stream>>>(pairExpert, padStart, cursor, row2pair);
  k_gather<<<CAP_ROWS, 256, 0, stream>>>(x, row2pair, XR);

  k_gemm1<<<dim3(D_FF / 128, MAX_TILES), 256, 0, stream>>>(XR, W1T, b1, H, t2e, trow);
  k_gemm2<<<MAX_TILES * (D_MODEL / 128), 256, 0, stream>>>(H, W2T, b2, Ypair, row2pair, pairW, t2e, trow);
  k_combine<<<(size_t)T_TOK * D_MODEL / 4 / 256, 256, 0, stream>>>(Ypair, out);
}

// Round 3
// 864.074 us; speedup vs baseline: 1.0522x; 1.0307x over previous
//
#include <hip/hip_runtime.h>
#include <hip/hip_bf16.h>
#include <math.h>

// ---------------- problem constants ----------------
#define D_MODEL 1024
#define N_EXP   8
#define D_FF    4096
#define T_TOK   8192
#define NPAIR   (T_TOK * 2)              // 16384 token-expert pairs (top-2)
#define CAP_ROWS (NPAIR + N_EXP * 128)   // 17408: worst-case padded rows
#define MAX_TILES (CAP_ROWS / 128)       // 136 M-tiles worst case (divisible by 8)

typedef __attribute__((ext_vector_type(4)))  float  f32x4;
typedef __attribute__((ext_vector_type(16))) float  f32x16;
typedef __attribute__((ext_vector_type(8)))  __bf16 bf16x8;
typedef __attribute__((ext_vector_type(4)))  __bf16 bf16x4;

// ---------------- workspace layout (bytes) ----------------
#define OFF_W1T   0
#define OFF_W2T   67108864
#define OFF_H     134217728
#define OFF_XR    276824064
#define OFF_META  312475648
#define M_PAIREXP 0         // int[16384]
#define M_PAIRW   65536     // float[16384]
#define M_ROW2P   131072    // int[17408]
#define M_COUNTS  200704    // int[8]
#define M_PADST   200736    // int[8]
#define M_CURSOR  200768    // int[8*32] (padded lines)
#define M_T2E     201792    // int[136]
#define M_TROW    202336    // int[136]

__device__ __forceinline__ void async_copy16(const void* g, void* s) {
  __builtin_amdgcn_global_load_lds(
      (const __attribute__((address_space(1))) void*)g,
      (__attribute__((address_space(3))) void*)s, 16, 0, 0);
}

// tanh-form gelu via sigmoid: gelu(v) = v * sigmoid(1.595769*(v + 0.044715 v^3))
// max abs deviation from exact-erf gelu ~1e-3; ~7 VALU ops vs ~20 for erff.
__device__ __forceinline__ float gelu_fast(float v) {
  float u = 1.5957691216057308f * (v + 0.044715f * v * v * v);
  return v * __builtin_amdgcn_rcpf(1.f + __expf(-u));
}

// ---------------- gating: logits, softmax, top-2 ----------------
__global__ void k_gate(const float* __restrict__ x, const float* __restrict__ Wg,
                       const float* __restrict__ bg, float* __restrict__ logits_out,
                       int* __restrict__ pairExpert, float* __restrict__ pairW) {
  const int t    = blockIdx.x * 4 + (threadIdx.x >> 6);
  const int lane = threadIdx.x & 63;
  const float* xp = x + (size_t)t * D_MODEL;
  float acc[8];
#pragma unroll
  for (int e = 0; e < 8; e++) acc[e] = 0.f;
#pragma unroll
  for (int i = 0; i < 16; i++) {
    int d = i * 64 + lane;
    float xv = xp[d];
    const float4* wr = (const float4*)(Wg + d * 8);
    float4 w0 = wr[0], w1 = wr[1];
    acc[0] += xv * w0.x; acc[1] += xv * w0.y; acc[2] += xv * w0.z; acc[3] += xv * w0.w;
    acc[4] += xv * w1.x; acc[5] += xv * w1.y; acc[6] += xv * w1.z; acc[7] += xv * w1.w;
  }
#pragma unroll
  for (int e = 0; e < 8; e++)
#pragma unroll
    for (int off = 32; off > 0; off >>= 1) acc[e] += __shfl_down(acc[e], off);
  if (lane == 0) {
    float l[8];
#pragma unroll
    for (int e = 0; e < 8; e++) { l[e] = acc[e] + bg[e]; logits_out[t * 8 + e] = l[e]; }
    float m = l[0];
#pragma unroll
    for (int e = 1; e < 8; e++) m = fmaxf(m, l[e]);
    float p[8], s = 0.f;
#pragma unroll
    for (int e = 0; e < 8; e++) { p[e] = expf(l[e] - m); s += p[e]; }
    float inv = 1.0f / s;
    int i1 = 0;
#pragma unroll
    for (int e = 1; e < 8; e++) if (l[e] > l[i1]) i1 = e;
    int i2 = (i1 == 0) ? 1 : 0;
#pragma unroll
    for (int e = 0; e < 8; e++) if (e != i1 && l[e] > l[i2]) i2 = e;
    pairExpert[t * 2 + 0] = i1; pairW[t * 2 + 0] = p[i1] * inv;
    pairExpert[t * 2 + 1] = i2; pairW[t * 2 + 1] = p[i2] * inv;
  }
}

// ---------------- routing metadata ----------------
__global__ void k_init(int* __restrict__ row2pair) {
  int i = blockIdx.x * 256 + threadIdx.x;
  if (i < CAP_ROWS) row2pair[i] = -1;
}

__global__ void k_offsets(const int* __restrict__ pairExpert, int* __restrict__ counts,
                          int* __restrict__ padStart, int* __restrict__ cursor,
                          int* __restrict__ t2e, int* __restrict__ trow) {
  __shared__ int hist[8];
  int tid = threadIdx.x;
  if (tid < 8) hist[tid] = 0;
  __syncthreads();
  for (int i = tid; i < NPAIR; i += 256) atomicAdd(&hist[pairExpert[i]], 1);
  __syncthreads();
  if (tid == 0) {
    int run = 0, nt = 0;
    for (int e = 0; e < 8; e++) {
      counts[e] = hist[e]; padStart[e] = run; cursor[e * 32] = 0;
      int tiles = (hist[e] + 127) >> 7;
      for (int i = 0; i < tiles; i++) { t2e[nt] = e; trow[nt] = run + i * 128; nt++; }
      run += tiles * 128;
    }
    for (; nt < MAX_TILES; nt++) t2e[nt] = -1;
  }
}

__global__ void k_place(const int* __restrict__ pairExpert, const int* __restrict__ padStart,
                        int* __restrict__ cursor, int* __restrict__ row2pair) {
  int p = blockIdx.x * 256 + threadIdx.x;
  if (p >= NPAIR) return;
  int e = pairExpert[p];
  int r = atomicAdd(&cursor[e * 32], 1);
  row2pair[padStart[e] + r] = p;
}

// ---------------- gather x rows -> routed bf16 ----------------
__global__ void k_gather(const float* __restrict__ x, const int* __restrict__ row2pair,
                         __bf16* __restrict__ XR) {
  int row = blockIdx.x;
  int pair = row2pair[row];
  int c = threadIdx.x * 4;
  __bf16* dst = XR + (size_t)row * D_MODEL + c;
  if (pair < 0) {
    bf16x4 z = {(__bf16)0.f, (__bf16)0.f, (__bf16)0.f, (__bf16)0.f};
    *(bf16x4*)dst = z;
  } else {
    int t = pair >> 1;
    float4 v = *(const float4*)(x + (size_t)t * D_MODEL + c);
    bf16x4 o = {(__bf16)v.x, (__bf16)v.y, (__bf16)v.z, (__bf16)v.w};
    *(bf16x4*)dst = o;
  }
}

// ---------------- transpose-convert weights: fp32 [E][R][C] -> bf16 [E][C][R] ----
__global__ void k_convT(const float* __restrict__ in, __bf16* __restrict__ out,
                        int R, int C) {
  __shared__ __bf16 tile[64][68];
  int e = blockIdx.z;
  const float* ip = in + (size_t)e * R * C + (size_t)(blockIdx.y * 64) * C + blockIdx.x * 64;
  __bf16* op = out + (size_t)e * R * C + (size_t)(blockIdx.x * 64) * R + blockIdx.y * 64;
#pragma unroll
  for (int it = 0; it < 4; it++) {
    int idx = it * 1024 + threadIdx.x * 4;
    int lr = idx >> 6, lc = idx & 63;
    float4 v = *(const float4*)(ip + (size_t)lr * C + lc);
    bf16x4 o = {(__bf16)v.x, (__bf16)v.y, (__bf16)v.z, (__bf16)v.w};
    *(bf16x4*)&tile[lr][lc] = o;
  }
  __syncthreads();
#pragma unroll
  for (int it = 0; it < 4; it++) {
    int idx = it * 1024 + threadIdx.x * 4;
    int lc = idx >> 6, lr = idx & 63;
    bf16x4 o = {tile[lr + 0][lc], tile[lr + 1][lc], tile[lr + 2][lc], tile[lr + 3][lc]};
    *(bf16x4*)(op + (size_t)lc * R + lr) = o;
  }
}

// ---------------- GEMM1: h = gelu(XR @ W1[e] + b1[e]) -> bf16 (32x32x16 MFMA) -------
__global__ __launch_bounds__(256) void k_gemm1(
    const __bf16* __restrict__ XR, const __bf16* __restrict__ W1T,
    const float* __restrict__ b1, __bf16* __restrict__ H,
    const int* __restrict__ t2e, const int* __restrict__ trow) {
  __shared__ __align__(16) __bf16 sA[128 * 32];
  __shared__ __align__(16) __bf16 sB[128 * 32];
  const int mt = blockIdx.y;
  const int e = t2e[mt];
  if (e < 0) return;
  const int rowBase = trow[mt];
  const int n0 = blockIdx.x * 128;
  const __bf16* Ab = XR + (size_t)rowBase * D_MODEL;
  const __bf16* Bb = W1T + (size_t)e * D_FF * D_MODEL + (size_t)n0 * D_MODEL;

  const int tid = threadIdx.x;
  const int rA = tid >> 2;
  const int kA = (tid & 3) * 8;
  const int lane = tid & 63;
  const int wave = tid >> 6;
  const int wm = (wave >> 1) * 64, wn = (wave & 1) * 64;
  const int l31 = lane & 31;
  const int half = lane >> 5;

  f32x16 acc[2][2];
#pragma unroll
  for (int i = 0; i < 2; i++)
#pragma unroll
    for (int j = 0; j < 2; j++) acc[i][j] = (f32x16)(0.f);

  for (int k0 = 0; k0 < D_MODEL; k0 += 32) {
    async_copy16(Ab + (size_t)rA * D_MODEL + k0 + kA,        (char*)sA + tid * 16);
    async_copy16(Ab + (size_t)(rA + 64) * D_MODEL + k0 + kA, (char*)sA + tid * 16 + 4096);
    async_copy16(Bb + (size_t)rA * D_MODEL + k0 + kA,        (char*)sB + tid * 16);
    async_copy16(Bb + (size_t)(rA + 64) * D_MODEL + k0 + kA, (char*)sB + tid * 16 + 4096);
    __syncthreads();
    bf16x8 af[2][2], bfr[2][2];  // [tile][k-chunk]
#pragma unroll
    for (int ti = 0; ti < 2; ti++)
#pragma unroll
      for (int kc = 0; kc < 2; kc++) {
        af[ti][kc]  = *(const bf16x8*)(sA + (wm + ti * 32 + l31) * 32 + kc * 16 + half * 8);
        bfr[ti][kc] = *(const bf16x8*)(sB + (wn + ti * 32 + l31) * 32 + kc * 16 + half * 8);
      }
#pragma unroll
    for (int kc = 0; kc < 2; kc++)
#pragma unroll
      for (int ti = 0; ti < 2; ti++)
#pragma unroll
        for (int tj = 0; tj < 2; tj++)
          acc[ti][tj] = __builtin_amdgcn_mfma_f32_32x32x16_bf16(af[ti][kc], bfr[tj][kc], acc[ti][tj], 0, 0, 0);
    __syncthreads();
  }
  // epilogue: C/D layout col=lane&31, row=(r&3)+8*(r>>2)+4*half
  int   colv[2]; float biasv[2];
#pragma unroll
  for (int tj = 0; tj < 2; tj++) {
    colv[tj] = n0 + wn + tj * 32 + l31;
    biasv[tj] = b1[e * D_FF + colv[tj]];
  }
#pragma unroll
  for (int ti = 0; ti < 2; ti++)
#pragma unroll
    for (int r = 0; r < 16; r++) {
      size_t row = (size_t)rowBase + wm + ti * 32 + (r & 3) + 8 * (r >> 2) + 4 * half;
#pragma unroll
      for (int tj = 0; tj < 2; tj++)
        H[row * D_FF + colv[tj]] = (__bf16)gelu_fast(acc[ti][tj][r] + biasv[tj]);
    }
}

// ---------------- GEMM2: y = (H @ W2[e] + b2[e]) * w -> Ypair (32x32x16 MFMA) -------
// 1D grid, XCD-aware swizzle: XCD = mt % 8, n-tiles fastest within an XCD.
__global__ __launch_bounds__(256) void k_gemm2(
    const __bf16* __restrict__ H, const __bf16* __restrict__ W2T,
    const float* __restrict__ b2, float* __restrict__ Ypair,
    const int* __restrict__ row2pair, const float* __restrict__ pairW,
    const int* __restrict__ t2e, const int* __restrict__ trow) {
  __shared__ __align__(16) __bf16 sA[128 * 32];
  __shared__ __align__(16) __bf16 sB[128 * 32];
  const int b = blockIdx.x;
  const int mt = (b >> 6) * 8 + (b & 7);
  const int nb = (b >> 3) & 7;
  const int e = t2e[mt];
  if (e < 0) return;
  const int rowBase = trow[mt];
  const int n0 = nb * 128;
  const __bf16* Ab = H + (size_t)rowBase * D_FF;
  const __bf16* Bb = W2T + (size_t)e * D_MODEL * D_FF + (size_t)n0 * D_FF;

  const int tid = threadIdx.x;
  const int rA = tid >> 2;
  const int kA = (tid & 3) * 8;
  const int lane = tid & 63;
  const int wave = tid >> 6;
  const int wm = (wave >> 1) * 64, wn = (wave & 1) * 64;
  const int l31 = lane & 31;
  const int half = lane >> 5;

  f32x16 acc[2][2];
#pragma unroll
  for (int i = 0; i < 2; i++)
#pragma unroll
    for (int j = 0; j < 2; j++) acc[i][j] = (f32x16)(0.f);

  for (int k0 = 0; k0 < D_FF; k0 += 32) {
    async_copy16(Ab + (size_t)rA * D_FF + k0 + kA,        (char*)sA + tid * 16);
    async_copy16(Ab + (size_t)(rA + 64) * D_FF + k0 + kA, (char*)sA + tid * 16 + 4096);
    async_copy16(Bb + (size_t)rA * D_FF + k0 + kA,        (char*)sB + tid * 16);
    async_copy16(Bb + (size_t)(rA + 64) * D_FF + k0 + kA, (char*)sB + tid * 16 + 4096);
    __syncthreads();
    bf16x8 af[2][2], bfr[2][2];
#pragma unroll
    for (int ti = 0; ti < 2; ti++)
#pragma unroll
      for (int kc = 0; kc < 2; kc++) {
        af[ti][kc]  = *(const bf16x8*)(sA + (wm + ti * 32 + l31) * 32 + kc * 16 + half * 8);
        bfr[ti][kc] = *(const bf16x8*)(sB + (wn + ti * 32 + l31) * 32 + kc * 16 + half * 8);
      }
#pragma unroll
    for (int kc = 0; kc < 2; kc++)
#pragma unroll
      for (int ti = 0; ti < 2; ti++)
#pragma unroll
        for (int tj = 0; tj < 2; tj++)
          acc[ti][tj] = __builtin_amdgcn_mfma_f32_32x32x16_bf16(af[ti][kc], bfr[tj][kc], acc[ti][tj], 0, 0, 0);
    __syncthreads();
  }
  int colv[2]; float biasv[2];
#pragma unroll
  for (int tj = 0; tj < 2; tj++) {
    colv[tj] = n0 + wn + tj * 32 + l31;
    biasv[tj] = b2[e * D_MODEL + colv[tj]];
  }
#pragma unroll
  for (int ti = 0; ti < 2; ti++)
#pragma unroll
    for (int r = 0; r < 16; r++) {
      int row = rowBase + wm + ti * 32 + (r & 3) + 8 * (r >> 2) + 4 * half;
      int pair = row2pair[row];
      if (pair < 0) continue;
      float w = pairW[pair];
#pragma unroll
      for (int tj = 0; tj < 2; tj++)
        Ypair[(size_t)pair * D_MODEL + colv[tj]] = w * (acc[ti][tj][r] + biasv[tj]);
    }
}

// ---------------- combine: out[t] = y[t,slot0] + y[t,slot1] ----------------
__global__ void k_combine(const float* __restrict__ Ypair, float* __restrict__ out) {
  size_t idx = (size_t)blockIdx.x * 256 + threadIdx.x;  // t*256 + c4
  size_t t = idx >> 8, c4 = idx & 255;
  const float4* y4 = (const float4*)Ypair;
  float4 a = y4[(2 * t) * 256 + c4];
  float4 b = y4[(2 * t + 1) * 256 + c4];
  float4 o = {a.x + b.x, a.y + b.y, a.z + b.z, a.w + b.w};
  ((float4*)out)[idx] = o;
}

extern "C" void kernel_launch(void* const* d_in, const int* in_sizes, int n_in,
                              void* d_out, int out_size, void* d_ws, size_t ws_size,
                              hipStream_t stream) {
  const float* x  = (const float*)d_in[0];
  const float* Wg = (const float*)d_in[1];
  const float* bg = (const float*)d_in[2];
  const float* W1 = (const float*)d_in[3];
  const float* b1 = (const float*)d_in[4];
  const float* W2 = (const float*)d_in[5];
  const float* b2 = (const float*)d_in[6];
  float* out        = (float*)d_out;
  float* logits_out = out + (size_t)T_TOK * D_MODEL;

  char* ws = (char*)d_ws;
  __bf16* W1T = (__bf16*)(ws + OFF_W1T);
  __bf16* W2T = (__bf16*)(ws + OFF_W2T);
  __bf16* H   = (__bf16*)(ws + OFF_H);
  __bf16* XR  = (__bf16*)(ws + OFF_XR);
  float* Ypair = (float*)(ws + OFF_W1T);  // alias: W1T dead after GEMM1
  char* meta = ws + OFF_META;
  int*   pairExpert = (int*)(meta + M_PAIREXP);
  float* pairW      = (float*)(meta + M_PAIRW);
  int*   row2pair   = (int*)(meta + M_ROW2P);
  int*   counts     = (int*)(meta + M_COUNTS);
  int*   padStart   = (int*)(meta + M_PADST);
  int*   cursor     = (int*)(meta + M_CURSOR);
  int*   t2e        = (int*)(meta + M_T2E);
  int*   trow       = (int*)(meta + M_TROW);

  // weight convert+transpose: W1 [E][1024][4096] -> W1T [E][4096][1024]
  k_convT<<<dim3(D_FF / 64, D_MODEL / 64, N_EXP), 256, 0, stream>>>(W1, W1T, D_MODEL, D_FF);
  // W2 [E][4096][1024] -> W2T [E][1024][4096]
  k_convT<<<dim3(D_MODEL / 64, D_FF / 64, N_EXP), 256, 0, stream>>>(W2, W2T, D_FF, D_MODEL);

  k_init<<<(CAP_ROWS + 255) / 256, 256, 0, stream>>>(row2pair);
  k_gate<<<T_TOK / 4, 256, 0, stream>>>(x, Wg, bg, logits_out, pairExpert, pairW);
  k_offsets<<<1, 256, 0, stream>>>(pairExpert, counts, padStart, cursor, t2e, trow);
  k_place<<<NPAIR / 256, 256, 0, stream>>>(pairExpert, padStart, cursor, row2pair);
  k_gather<<<CAP_ROWS, 256, 0, stream>>>(x, row2pair, XR);

  k_gemm1<<<dim3(D_FF / 128, MAX_TILES), 256, 0, stream>>>(XR, W1T, b1, H, t2e, trow);
  k_gemm2<<<MAX_TILES * (D_MODEL / 128), 256, 0, stream>>>(H, W2T, b2, Ypair, row2pair, pairW, t2e, trow);
  k_combine<<<(size_t)T_TOK * D_MODEL / 4 / 256, 256, 0, stream>>>(Ypair, out);
}

// Round 4
// 836.384 us; speedup vs baseline: 1.0870x; 1.0331x over previous
//
#include <hip/hip_runtime.h>
#include <hip/hip_bf16.h>
#include <math.h>

// ---------------- problem constants ----------------
#define D_MODEL 1024
#define N_EXP   8
#define D_FF    4096
#define T_TOK   8192
#define NPAIR   (T_TOK * 2)              // 16384 token-expert pairs (top-2)
#define CAP_ROWS (NPAIR + N_EXP * 128)   // 17408: worst-case padded rows
#define MAX_TILES (CAP_ROWS / 128)       // 136 M-tiles worst case (divisible by 8)

// LDS chunked layout: 16 rows x 64B = 1024B chunk, +32B pad between chunks.
// Write side (global_load_lds) is contiguous within a chunk (wave-uniform base,
// lane*16); the 32B inter-chunk skew rotates start banks so the 32x32-MFMA
// fragment reads (32 lanes, stride 64B) cover all 32 banks -> conflict-free.
#define CHUNK_STRIDE 1056
#define TILE_BYTES   (8 * CHUNK_STRIDE)   // 128 rows = 8 chunks

typedef __attribute__((ext_vector_type(4)))  float  f32x4;
typedef __attribute__((ext_vector_type(16))) float  f32x16;
typedef __attribute__((ext_vector_type(8)))  __bf16 bf16x8;
typedef __attribute__((ext_vector_type(4)))  __bf16 bf16x4;

// ---------------- workspace layout (bytes) ----------------
#define OFF_W1T   0
#define OFF_W2T   67108864
#define OFF_H     134217728
#define OFF_XR    276824064
#define OFF_META  312475648
#define M_PAIREXP 0         // int[16384]
#define M_PAIRW   65536     // float[16384]
#define M_ROW2P   131072    // int[17408]
#define M_COUNTS  200704    // int[8]
#define M_PADST   200736    // int[8]
#define M_CURSOR  200768    // int[8*32] (padded lines)
#define M_T2E     201792    // int[136]
#define M_TROW    202336    // int[136]

__device__ __forceinline__ void async_copy16(const void* g, void* s) {
  __builtin_amdgcn_global_load_lds(
      (const __attribute__((address_space(1))) void*)g,
      (__attribute__((address_space(3))) void*)s, 16, 0, 0);
}

// tanh-form gelu via sigmoid: gelu(v) = v * sigmoid(1.595769*(v + 0.044715 v^3))
__device__ __forceinline__ float gelu_fast(float v) {
  float u = 1.5957691216057308f * (v + 0.044715f * v * v * v);
  return v * __builtin_amdgcn_rcpf(1.f + __expf(-u));
}

// ---------------- gating: logits, softmax, top-2 ----------------
__global__ void k_gate(const float* __restrict__ x, const float* __restrict__ Wg,
                       const float* __restrict__ bg, float* __restrict__ logits_out,
                       int* __restrict__ pairExpert, float* __restrict__ pairW) {
  const int t    = blockIdx.x * 4 + (threadIdx.x >> 6);
  const int lane = threadIdx.x & 63;
  const float* xp = x + (size_t)t * D_MODEL;
  float acc[8];
#pragma unroll
  for (int e = 0; e < 8; e++) acc[e] = 0.f;
#pragma unroll
  for (int i = 0; i < 16; i++) {
    int d = i * 64 + lane;
    float xv = xp[d];
    const float4* wr = (const float4*)(Wg + d * 8);
    float4 w0 = wr[0], w1 = wr[1];
    acc[0] += xv * w0.x; acc[1] += xv * w0.y; acc[2] += xv * w0.z; acc[3] += xv * w0.w;
    acc[4] += xv * w1.x; acc[5] += xv * w1.y; acc[6] += xv * w1.z; acc[7] += xv * w1.w;
  }
#pragma unroll
  for (int e = 0; e < 8; e++)
#pragma unroll
    for (int off = 32; off > 0; off >>= 1) acc[e] += __shfl_down(acc[e], off);
  if (lane == 0) {
    float l[8];
#pragma unroll
    for (int e = 0; e < 8; e++) { l[e] = acc[e] + bg[e]; logits_out[t * 8 + e] = l[e]; }
    float m = l[0];
#pragma unroll
    for (int e = 1; e < 8; e++) m = fmaxf(m, l[e]);
    float p[8], s = 0.f;
#pragma unroll
    for (int e = 0; e < 8; e++) { p[e] = expf(l[e] - m); s += p[e]; }
    float inv = 1.0f / s;
    int i1 = 0;
#pragma unroll
    for (int e = 1; e < 8; e++) if (l[e] > l[i1]) i1 = e;
    int i2 = (i1 == 0) ? 1 : 0;
#pragma unroll
    for (int e = 0; e < 8; e++) if (e != i1 && l[e] > l[i2]) i2 = e;
    pairExpert[t * 2 + 0] = i1; pairW[t * 2 + 0] = p[i1] * inv;
    pairExpert[t * 2 + 1] = i2; pairW[t * 2 + 1] = p[i2] * inv;
  }
}

// ---------------- routing metadata ----------------
__global__ void k_init(int* __restrict__ row2pair) {
  int i = blockIdx.x * 256 + threadIdx.x;
  if (i < CAP_ROWS) row2pair[i] = -1;
}

__global__ void k_offsets(const int* __restrict__ pairExpert, int* __restrict__ counts,
                          int* __restrict__ padStart, int* __restrict__ cursor,
                          int* __restrict__ t2e, int* __restrict__ trow) {
  __shared__ int hist[8];
  int tid = threadIdx.x;
  if (tid < 8) hist[tid] = 0;
  __syncthreads();
  for (int i = tid; i < NPAIR; i += 256) atomicAdd(&hist[pairExpert[i]], 1);
  __syncthreads();
  if (tid == 0) {
    int run = 0, nt = 0;
    for (int e = 0; e < 8; e++) {
      counts[e] = hist[e]; padStart[e] = run; cursor[e * 32] = 0;
      int tiles = (hist[e] + 127) >> 7;
      for (int i = 0; i < tiles; i++) { t2e[nt] = e; trow[nt] = run + i * 128; nt++; }
      run += tiles * 128;
    }
    for (; nt < MAX_TILES; nt++) t2e[nt] = -1;
  }
}

__global__ void k_place(const int* __restrict__ pairExpert, const int* __restrict__ padStart,
                        int* __restrict__ cursor, int* __restrict__ row2pair) {
  int p = blockIdx.x * 256 + threadIdx.x;
  if (p >= NPAIR) return;
  int e = pairExpert[p];
  int r = atomicAdd(&cursor[e * 32], 1);
  row2pair[padStart[e] + r] = p;
}

// ---------------- gather x rows -> routed bf16 ----------------
__global__ void k_gather(const float* __restrict__ x, const int* __restrict__ row2pair,
                         __bf16* __restrict__ XR) {
  int row = blockIdx.x;
  int pair = row2pair[row];
  int c = threadIdx.x * 4;
  __bf16* dst = XR + (size_t)row * D_MODEL + c;
  if (pair < 0) {
    bf16x4 z = {(__bf16)0.f, (__bf16)0.f, (__bf16)0.f, (__bf16)0.f};
    *(bf16x4*)dst = z;
  } else {
    int t = pair >> 1;
    float4 v = *(const float4*)(x + (size_t)t * D_MODEL + c);
    bf16x4 o = {(__bf16)v.x, (__bf16)v.y, (__bf16)v.z, (__bf16)v.w};
    *(bf16x4*)dst = o;
  }
}

// ---------------- transpose-convert weights: fp32 [E][R][C] -> bf16 [E][C][R] ----
__global__ void k_convT(const float* __restrict__ in, __bf16* __restrict__ out,
                        int R, int C) {
  __shared__ __bf16 tile[64][68];
  int e = blockIdx.z;
  const float* ip = in + (size_t)e * R * C + (size_t)(blockIdx.y * 64) * C + blockIdx.x * 64;
  __bf16* op = out + (size_t)e * R * C + (size_t)(blockIdx.x * 64) * R + blockIdx.y * 64;
#pragma unroll
  for (int it = 0; it < 4; it++) {
    int idx = it * 1024 + threadIdx.x * 4;
    int lr = idx >> 6, lc = idx & 63;
    float4 v = *(const float4*)(ip + (size_t)lr * C + lc);
    bf16x4 o = {(__bf16)v.x, (__bf16)v.y, (__bf16)v.z, (__bf16)v.w};
    *(bf16x4*)&tile[lr][lc] = o;
  }
  __syncthreads();
#pragma unroll
  for (int it = 0; it < 4; it++) {
    int idx = it * 1024 + threadIdx.x * 4;
    int lc = idx >> 6, lr = idx & 63;
    bf16x4 o = {tile[lr + 0][lc], tile[lr + 1][lc], tile[lr + 2][lc], tile[lr + 3][lc]};
    *(bf16x4*)(op + (size_t)lc * R + lr) = o;
  }
}

// ---------------- GEMM1: h = gelu(XR @ W1[e] + b1[e]) -> bf16 (32x32x16 MFMA) -------
__global__ __launch_bounds__(256) void k_gemm1(
    const __bf16* __restrict__ XR, const __bf16* __restrict__ W1T,
    const float* __restrict__ b1, __bf16* __restrict__ H,
    const int* __restrict__ t2e, const int* __restrict__ trow) {
  __shared__ __align__(16) char sA[TILE_BYTES];
  __shared__ __align__(16) char sB[TILE_BYTES];
  const int mt = blockIdx.y;
  const int e = t2e[mt];
  if (e < 0) return;
  const int rowBase = trow[mt];
  const int n0 = blockIdx.x * 128;
  const __bf16* Ab = XR + (size_t)rowBase * D_MODEL;
  const __bf16* Bb = W1T + (size_t)e * D_FF * D_MODEL + (size_t)n0 * D_MODEL;

  const int tid = threadIdx.x;
  const int rA = tid >> 2;
  const int kA = (tid & 3) * 8;
  const int lane = tid & 63;
  const int wave = tid >> 6;
  const int wm = (wave >> 1) * 64, wn = (wave & 1) * 64;
  const int l31 = lane & 31;
  const int half = lane >> 5;

  // LDS staging dests: chunk = wave (rows w*16..w*16+15), +4 for rows 64..127
  char* dA0 = sA + wave * CHUNK_STRIDE + lane * 16;
  char* dA1 = sA + (4 + wave) * CHUNK_STRIDE + lane * 16;
  char* dB0 = sB + wave * CHUNK_STRIDE + lane * 16;
  char* dB1 = sB + (4 + wave) * CHUNK_STRIDE + lane * 16;
  // fragment read bases (chunked addressing)
  int mA0 = wm + l31, mA1 = wm + 32 + l31;
  const char* rA0 = sA + (mA0 >> 4) * CHUNK_STRIDE + (mA0 & 15) * 64 + half * 16;
  const char* rA1 = sA + (mA1 >> 4) * CHUNK_STRIDE + (mA1 & 15) * 64 + half * 16;
  int nB0 = wn + l31, nB1 = wn + 32 + l31;
  const char* rB0 = sB + (nB0 >> 4) * CHUNK_STRIDE + (nB0 & 15) * 64 + half * 16;
  const char* rB1 = sB + (nB1 >> 4) * CHUNK_STRIDE + (nB1 & 15) * 64 + half * 16;

  f32x16 acc[2][2];
#pragma unroll
  for (int i = 0; i < 2; i++)
#pragma unroll
    for (int j = 0; j < 2; j++) acc[i][j] = (f32x16)(0.f);

  for (int k0 = 0; k0 < D_MODEL; k0 += 32) {
    async_copy16(Ab + (size_t)rA * D_MODEL + k0 + kA,        dA0);
    async_copy16(Ab + (size_t)(rA + 64) * D_MODEL + k0 + kA, dA1);
    async_copy16(Bb + (size_t)rA * D_MODEL + k0 + kA,        dB0);
    async_copy16(Bb + (size_t)(rA + 64) * D_MODEL + k0 + kA, dB1);
    __syncthreads();
    bf16x8 af[2][2], bfr[2][2];  // [tile][k-chunk]
#pragma unroll
    for (int kc = 0; kc < 2; kc++) {
      af[0][kc]  = *(const bf16x8*)(rA0 + kc * 32);
      af[1][kc]  = *(const bf16x8*)(rA1 + kc * 32);
      bfr[0][kc] = *(const bf16x8*)(rB0 + kc * 32);
      bfr[1][kc] = *(const bf16x8*)(rB1 + kc * 32);
    }
#pragma unroll
    for (int kc = 0; kc < 2; kc++)
#pragma unroll
      for (int ti = 0; ti < 2; ti++)
#pragma unroll
        for (int tj = 0; tj < 2; tj++)
          acc[ti][tj] = __builtin_amdgcn_mfma_f32_32x32x16_bf16(af[ti][kc], bfr[tj][kc], acc[ti][tj], 0, 0, 0);
    __syncthreads();
  }
  // epilogue: C/D layout col=lane&31, row=(r&3)+8*(r>>2)+4*half
  int   colv[2]; float biasv[2];
#pragma unroll
  for (int tj = 0; tj < 2; tj++) {
    colv[tj] = n0 + wn + tj * 32 + l31;
    biasv[tj] = b1[e * D_FF + colv[tj]];
  }
#pragma unroll
  for (int ti = 0; ti < 2; ti++)
#pragma unroll
    for (int r = 0; r < 16; r++) {
      size_t row = (size_t)rowBase + wm + ti * 32 + (r & 3) + 8 * (r >> 2) + 4 * half;
#pragma unroll
      for (int tj = 0; tj < 2; tj++)
        H[row * D_FF + colv[tj]] = (__bf16)gelu_fast(acc[ti][tj][r] + biasv[tj]);
    }
}

// ---------------- GEMM2: y = (H @ W2[e] + b2[e]) * w -> Ypair (32x32x16 MFMA) -------
// 1D grid, XCD-aware swizzle: XCD = mt % 8, n-tiles fastest within an XCD.
__global__ __launch_bounds__(256) void k_gemm2(
    const __bf16* __restrict__ H, const __bf16* __restrict__ W2T,
    const float* __restrict__ b2, float* __restrict__ Ypair,
    const int* __restrict__ row2pair, const float* __restrict__ pairW,
    const int* __restrict__ t2e, const int* __restrict__ trow) {
  __shared__ __align__(16) char sA[TILE_BYTES];
  __shared__ __align__(16) char sB[TILE_BYTES];
  const int b = blockIdx.x;
  const int mt = (b >> 6) * 8 + (b & 7);
  const int nb = (b >> 3) & 7;
  const int e = t2e[mt];
  if (e < 0) return;
  const int rowBase = trow[mt];
  const int n0 = nb * 128;
  const __bf16* Ab = H + (size_t)rowBase * D_FF;
  const __bf16* Bb = W2T + (size_t)e * D_MODEL * D_FF + (size_t)n0 * D_FF;

  const int tid = threadIdx.x;
  const int rA = tid >> 2;
  const int kA = (tid & 3) * 8;
  const int lane = tid & 63;
  const int wave = tid >> 6;
  const int wm = (wave >> 1) * 64, wn = (wave & 1) * 64;
  const int l31 = lane & 31;
  const int half = lane >> 5;

  char* dA0 = sA + wave * CHUNK_STRIDE + lane * 16;
  char* dA1 = sA + (4 + wave) * CHUNK_STRIDE + lane * 16;
  char* dB0 = sB + wave * CHUNK_STRIDE + lane * 16;
  char* dB1 = sB + (4 + wave) * CHUNK_STRIDE + lane * 16;
  int mA0 = wm + l31, mA1 = wm + 32 + l31;
  const char* rA0 = sA + (mA0 >> 4) * CHUNK_STRIDE + (mA0 & 15) * 64 + half * 16;
  const char* rA1 = sA + (mA1 >> 4) * CHUNK_STRIDE + (mA1 & 15) * 64 + half * 16;
  int nB0 = wn + l31, nB1 = wn + 32 + l31;
  const char* rB0 = sB + (nB0 >> 4) * CHUNK_STRIDE + (nB0 & 15) * 64 + half * 16;
  const char* rB1 = sB + (nB1 >> 4) * CHUNK_STRIDE + (nB1 & 15) * 64 + half * 16;

  f32x16 acc[2][2];
#pragma unroll
  for (int i = 0; i < 2; i++)
#pragma unroll
    for (int j = 0; j < 2; j++) acc[i][j] = (f32x16)(0.f);

  for (int k0 = 0; k0 < D_FF; k0 += 32) {
    async_copy16(Ab + (size_t)rA * D_FF + k0 + kA,        dA0);
    async_copy16(Ab + (size_t)(rA + 64) * D_FF + k0 + kA, dA1);
    async_copy16(Bb + (size_t)rA * D_FF + k0 + kA,        dB0);
    async_copy16(Bb + (size_t)(rA + 64) * D_FF + k0 + kA, dB1);
    __syncthreads();
    bf16x8 af[2][2], bfr[2][2];
#pragma unroll
    for (int kc = 0; kc < 2; kc++) {
      af[0][kc]  = *(const bf16x8*)(rA0 + kc * 32);
      af[1][kc]  = *(const bf16x8*)(rA1 + kc * 32);
      bfr[0][kc] = *(const bf16x8*)(rB0 + kc * 32);
      bfr[1][kc] = *(const bf16x8*)(rB1 + kc * 32);
    }
#pragma unroll
    for (int kc = 0; kc < 2; kc++)
#pragma unroll
      for (int ti = 0; ti < 2; ti++)
#pragma unroll
        for (int tj = 0; tj < 2; tj++)
          acc[ti][tj] = __builtin_amdgcn_mfma_f32_32x32x16_bf16(af[ti][kc], bfr[tj][kc], acc[ti][tj], 0, 0, 0);
    __syncthreads();
  }
  int colv[2]; float biasv[2];
#pragma unroll
  for (int tj = 0; tj < 2; tj++) {
    colv[tj] = n0 + wn + tj * 32 + l31;
    biasv[tj] = b2[e * D_MODEL + colv[tj]];
  }
#pragma unroll
  for (int ti = 0; ti < 2; ti++)
#pragma unroll
    for (int r = 0; r < 16; r++) {
      int row = rowBase + wm + ti * 32 + (r & 3) + 8 * (r >> 2) + 4 * half;
      int pair = row2pair[row];
      if (pair < 0) continue;
      float w = pairW[pair];
#pragma unroll
      for (int tj = 0; tj < 2; tj++)
        Ypair[(size_t)pair * D_MODEL + colv[tj]] = w * (acc[ti][tj][r] + biasv[tj]);
    }
}

// ---------------- combine: out[t] = y[t,slot0] + y[t,slot1] ----------------
__global__ void k_combine(const float* __restrict__ Ypair, float* __restrict__ out) {
  size_t idx = (size_t)blockIdx.x * 256 + threadIdx.x;  // t*256 + c4
  size_t t = idx >> 8, c4 = idx & 255;
  const float4* y4 = (const float4*)Ypair;
  float4 a = y4[(2 * t) * 256 + c4];
  float4 b = y4[(2 * t + 1) * 256 + c4];
  float4 o = {a.x + b.x, a.y + b.y, a.z + b.z, a.w + b.w};
  ((float4*)out)[idx] = o;
}

extern "C" void kernel_launch(void* const* d_in, const int* in_sizes, int n_in,
                              void* d_out, int out_size, void* d_ws, size_t ws_size,
                              hipStream_t stream) {
  const float* x  = (const float*)d_in[0];
  const float* Wg = (const float*)d_in[1];
  const float* bg = (const float*)d_in[2];
  const float* W1 = (const float*)d_in[3];
  const float* b1 = (const float*)d_in[4];
  const float* W2 = (const float*)d_in[5];
  const float* b2 = (const float*)d_in[6];
  float* out        = (float*)d_out;
  float* logits_out = out + (size_t)T_TOK * D_MODEL;

  char* ws = (char*)d_ws;
  __bf16* W1T = (__bf16*)(ws + OFF_W1T);
  __bf16* W2T = (__bf16*)(ws + OFF_W2T);
  __bf16* H   = (__bf16*)(ws + OFF_H);
  __bf16* XR  = (__bf16*)(ws + OFF_XR);
  float* Ypair = (float*)(ws + OFF_W1T);  // alias: W1T dead after GEMM1
  char* meta = ws + OFF_META;
  int*   pairExpert = (int*)(meta + M_PAIREXP);
  float* pairW      = (float*)(meta + M_PAIRW);
  int*   row2pair   = (int*)(meta + M_ROW2P);
  int*   counts     = (int*)(meta + M_COUNTS);
  int*   padStart   = (int*)(meta + M_PADST);
  int*   cursor     = (int*)(meta + M_CURSOR);
  int*   t2e        = (int*)(meta + M_T2E);
  int*   trow       = (int*)(meta + M_TROW);

  // weight convert+transpose: W1 [E][1024][4096] -> W1T [E][4096][1024]
  k_convT<<<dim3(D_FF / 64, D_MODEL / 64, N_EXP), 256, 0, stream>>>(W1, W1T, D_MODEL, D_FF);
  // W2 [E][4096][1024] -> W2T [E][1024][4096]
  k_convT<<<dim3(D_MODEL / 64, D_FF / 64, N_EXP), 256, 0, stream>>>(W2, W2T, D_FF, D_MODEL);

  k_init<<<(CAP_ROWS + 255) / 256, 256, 0, stream>>>(row2pair);
  k_gate<<<T_TOK / 4, 256, 0, stream>>>(x, Wg, bg, logits_out, pairExpert, pairW);
  k_offsets<<<1, 256, 0, stream>>>(pairExpert, counts, padStart, cursor, t2e, trow);
  k_place<<<NPAIR / 256, 256, 0, stream>>>(pairExpert, padStart, cursor, row2pair);
  k_gather<<<CAP_ROWS, 256, 0, stream>>>(x, row2pair, XR);

  k_gemm1<<<dim3(D_FF / 128, MAX_TILES), 256, 0, stream>>>(XR, W1T, b1, H, t2e, trow);
  k_gemm2<<<MAX_TILES * (D_MODEL / 128), 256, 0, stream>>>(H, W2T, b2, Ypair, row2pair, pairW, t2e, trow);
  k_combine<<<(size_t)T_TOK * D_MODEL / 4 / 256, 256, 0, stream>>>(Ypair, out);
}